// Round 4
// baseline (197.705 us; speedup 1.0000x reference)
//
#include <hip/hip_runtime.h>

typedef __bf16 bf16;
typedef __bf16 bf16x8 __attribute__((ext_vector_type(8)));
typedef __bf16 bf16x4 __attribute__((ext_vector_type(4)));
typedef float  f32x4  __attribute__((ext_vector_type(4)));
typedef float  f32x16 __attribute__((ext_vector_type(16)));
typedef unsigned int u32x4 __attribute__((ext_vector_type(4)));

#define MFMA16(a, b, c) __builtin_amdgcn_mfma_f32_16x16x32_bf16((a), (b), (c), 0, 0, 0)
#define MFMA32(a, b, c) __builtin_amdgcn_mfma_f32_32x32x16_bf16((a), (b), (c), 0, 0, 0)

// async global->LDS, 16B per lane, LDS dst = wave-uniform base + lane*16
__device__ __forceinline__ void gload_lds16(const bf16* g, bf16* l) {
  __builtin_amdgcn_global_load_lds(
      (const __attribute__((address_space(1))) void*)g,
      (__attribute__((address_space(3))) void*)l, 16, 0, 0);
}

// ---------------- prep kernels ----------------

__global__ __launch_bounds__(256) void cast_bf16_kernel(
    const float* __restrict__ in, bf16* __restrict__ out, int n4) {
  int i = blockIdx.x * 256 + threadIdx.x;
  if (i < n4) {
    float4 v = reinterpret_cast<const float4*>(in)[i];
    bf16x4 o;
    o[0] = (bf16)v.x; o[1] = (bf16)v.y; o[2] = (bf16)v.z; o[3] = (bf16)v.w;
    reinterpret_cast<bf16x4*>(out)[i] = o;
  }
}

__global__ __launch_bounds__(256) void transpose_cast_kernel(
    const float* __restrict__ W, bf16* __restrict__ Wt, int K, int N) {
  __shared__ bf16 tile[64 * 66];
  const int k0 = blockIdx.y * 64, n0 = blockIdx.x * 64;
  const int c = threadIdx.x & 63, rb = threadIdx.x >> 6;
#pragma unroll
  for (int p = 0; p < 16; ++p) {
    int r = p * 4 + rb;
    tile[c * 66 + r] = (bf16)W[(long)(k0 + r) * N + n0 + c];
  }
  __syncthreads();
#pragma unroll
  for (int p = 0; p < 16; ++p) {
    int r = p * 4 + rb;
    Wt[(long)(n0 + r) * K + k0 + c] = tile[r * 66 + c];
  }
}

// ---------------- GEMM: C(M,N) = A(M,K) @ Bt(N,K)^T, m97 structure ----------------
template <int EPI>
__global__ __launch_bounds__(256, 2) void gemm_bt(
    const bf16* __restrict__ A, const bf16* __restrict__ Bt,
    const float* __restrict__ bias, bf16* __restrict__ oQ,
    bf16* __restrict__ oK, bf16* __restrict__ oVT, float* __restrict__ oC,
    int K) {
  __shared__ bf16 As[128 * 64];
  __shared__ bf16 Bs[128 * 64];
  const int tid = threadIdx.x, lane = tid & 63, wid = tid >> 6;
  const int wr = wid >> 1, wc = wid & 1;
  const int brow = blockIdx.x * 128, bcol = blockIdx.y * 128;
  const int srow = lane >> 3, scol8 = (lane & 7) * 8;
  const int c15 = lane & 15, g = lane >> 4;

  f32x4 acc[4][4];
#pragma unroll
  for (int m = 0; m < 4; ++m)
#pragma unroll
    for (int n = 0; n < 4; ++n) acc[m][n] = f32x4{0.f, 0.f, 0.f, 0.f};

  const bf16* Ab = A + (long)brow * K + scol8;
  const bf16* Bb = Bt + (long)bcol * K + scol8;

  for (int k0 = 0; k0 < K; k0 += 64) {
#pragma unroll
    for (int i = 0; i < 4; ++i) {
      int c = wid * 4 + i;
      int row = c * 8 + srow;
      gload_lds16(Ab + (long)row * K + k0, &As[c * 512]);
    }
#pragma unroll
    for (int i = 0; i < 4; ++i) {
      int c = wid * 4 + i;
      int row = c * 8 + srow;
      gload_lds16(Bb + (long)row * K + k0, &Bs[c * 512]);
    }
    __syncthreads();
#pragma unroll
    for (int kk = 0; kk < 64; kk += 32) {
      bf16x8 a[4], b[4];
#pragma unroll
      for (int m = 0; m < 4; ++m)
        a[m] = *(const bf16x8*)&As[(wr * 64 + m * 16 + c15) * 64 + kk + g * 8];
#pragma unroll
      for (int n = 0; n < 4; ++n)
        b[n] = *(const bf16x8*)&Bs[(wc * 64 + n * 16 + c15) * 64 + kk + g * 8];
#pragma unroll
      for (int m = 0; m < 4; ++m)
#pragma unroll
        for (int n = 0; n < 4; ++n)
          acc[m][n] = MFMA16(a[m], b[n], acc[m][n]);
    }
    __syncthreads();
  }

#pragma unroll
  for (int n = 0; n < 4; ++n) {
    const int col = bcol + wc * 64 + n * 16 + c15;
    const float bv = bias[col];
    if (EPI == 0) {
      const int which = col >> 10, wi = col & 1023, h = wi >> 6, d = wi & 63;
      const float sc = (which == 0) ? 0.18033688011112042f : 1.0f;  // 0.125*log2(e)
#pragma unroll
      for (int m = 0; m < 4; ++m) {
        const int row0 = brow + wr * 64 + m * 16 + g * 4;
        const int bb = row0 >> 11, t0 = row0 & 2047;
        const long hb = bb * 16 + h;
        if (which == 2) {
          bf16x4 pv;
#pragma unroll
          for (int r = 0; r < 4; ++r) pv[r] = (bf16)(acc[m][n][r] + bv);
          *(bf16x4*)&oVT[(hb * 64 + d) * 2048 + t0] = pv;  // (b,h,d,t)
        } else {
          bf16* dst = ((which == 0) ? oQ : oK) + (hb * 2048 + t0) * 64 + d;
#pragma unroll
          for (int r = 0; r < 4; ++r)
            dst[(long)r * 64] = (bf16)((acc[m][n][r] + bv) * sc);
        }
      }
    } else {
#pragma unroll
      for (int m = 0; m < 4; ++m) {
        const long row = brow + wr * 64 + m * 16 + g * 4;
#pragma unroll
        for (int r = 0; r < 4; ++r) oC[(row + r) * 1024 + col] = acc[m][n][r] + bv;
      }
    }
  }
}

// ---------------- flash attention, 64 keys/iter, in-register softmax ----------
// 512 blocks x 4 waves; each wave owns 32 queries, 32 iters x 64 keys.
// S^T = mfma32(K, Q): lane(col=query, hi) holds key=(r&3)+8*(r>>2)+4*hi.
// Common path has ONE serial shuffle window (P-pack, 8 issued together):
// defer-max check via __any on per-half max; lrun kept as per-half partial.
__global__ __launch_bounds__(256, 2) void attn_kernel(
    const bf16* __restrict__ Q, const bf16* __restrict__ K,
    const bf16* __restrict__ VT, const int* __restrict__ mask,
    bf16* __restrict__ Aout) {
  __shared__ float sws[4][32];
  const int tid = threadIdx.x, lane = tid & 63, w = tid >> 6;
  const int col = lane & 31, hi = lane >> 5;
  const int bid = blockIdx.x;
  const int swz = (bid & 7) * 64 + (bid >> 3);  // XCD swizzle: 4 bh per XCD
  const int qt = swz & 15, bh = swz >> 4;
  const int b = bh >> 4, h = bh & 15;
  const int q0 = qt * 128 + w * 32;

  // Q B-frag (pre-scaled by 0.125*log2e in gemm epilogue)
  const bf16* Qp = Q + ((long)bh * 2048 + q0 + col) * 64 + hi * 8;
  bf16x8 bq[4];
#pragma unroll
  for (int dc = 0; dc < 4; ++dc) bq[dc] = *(const bf16x8*)(Qp + dc * 16);

  f32x16 o0, o1;
#pragma unroll
  for (int r = 0; r < 16; ++r) { o0[r] = 0.f; o1[r] = 0.f; }
  float mrun = -1e30f, lrun = 0.f;  // lrun = per-half partial until finalize

  const bf16* Kbh = K + (long)bh * 2048 * 64;
  const bf16* Vbh = VT + (long)bh * 64 * 2048;
  const int* mb = mask + b * 2048;

  auto body = [&](const bf16x8* ak, bf16x8* akn, int it) {
    const int kbase = it * 64;
    // V loads for all 64 keys (consumed at PV, ~400 cy later)
    bf16x8 bv[8];
    {
      const bf16* Vp = Vbh + (long)col * 2048 + kbase + hi * 8;
#pragma unroll
      for (int s = 0; s < 4; ++s) {
        bv[s] = *(const bf16x8*)(Vp + s * 16);
        bv[4 + s] = *(const bf16x8*)(Vp + 32 * 2048 + s * 16);
      }
    }
    const int mvA = mb[kbase + col], mvB = mb[kbase + 32 + col];
    // S^T = K @ Q^T, two independent accumulator chains
    f32x16 stA, stB;
#pragma unroll
    for (int r = 0; r < 16; ++r) { stA[r] = 0.f; stB[r] = 0.f; }
    __builtin_amdgcn_s_setprio(1);
#pragma unroll
    for (int dc = 0; dc < 4; ++dc) stA = MFMA32(ak[dc], bq[dc], stA);
#pragma unroll
    for (int dc = 0; dc < 4; ++dc) stB = MFMA32(ak[4 + dc], bq[dc], stB);
    __builtin_amdgcn_s_setprio(0);
    // prefetch next iteration's K (64 rows)
    {
      const int tn = (it + 1 < 32) ? it + 1 : 31;
      const bf16* Kp = Kbh + (long)(tn * 64 + col) * 64 + hi * 8;
#pragma unroll
      for (int dc = 0; dc < 4; ++dc) {
        akn[dc] = *(const bf16x8*)(Kp + dc * 16);
        akn[4 + dc] = *(const bf16x8*)(Kp + 32 * 64 + dc * 16);
      }
    }
    // mask (wave-uniform skip when all-ones)
    unsigned kmA = (unsigned)__ballot(mvA != 0);
    unsigned kmB = (unsigned)__ballot(mvB != 0);
    if (kmA != 0xffffffffu) {
#pragma unroll
      for (int r = 0; r < 16; ++r)
        if (!((kmA >> ((r & 3) + 8 * (r >> 2) + 4 * hi)) & 1)) stA[r] = -1e30f;
    }
    if (kmB != 0xffffffffu) {
#pragma unroll
      for (int r = 0; r < 16; ++r)
        if (!((kmB >> ((r & 3) + 8 * (r >> 2) + 4 * hi)) & 1)) stB[r] = -1e30f;
    }
    // per-half max over this lane's 32 scores (no cross-half shuffle on common path)
    float mx[8];
#pragma unroll
    for (int i = 0; i < 8; ++i)
      mx[i] = fmaxf(fmaxf(stA[2 * i], stA[2 * i + 1]),
                    fmaxf(stB[2 * i], stB[2 * i + 1]));
    float m0 = fmaxf(fmaxf(fmaxf(mx[0], mx[1]), fmaxf(mx[2], mx[3])),
                     fmaxf(fmaxf(mx[4], mx[5]), fmaxf(mx[6], mx[7])));
    // defer-max: rescale only when some row's max grew past THR=8 (log2 units)
    if (__any(m0 > mrun + 8.0f)) {
      float pm = fmaxf(m0, __shfl_xor(m0, 32));  // cross-half only on rare path
      float mnew = fmaxf(mrun, pm);
      float scale = __builtin_exp2f(mrun - mnew);
      mrun = mnew;
      lrun *= scale;
      if (hi == 0) sws[w][col] = scale;  // broadcast q-layout -> d-layout
      asm volatile("s_waitcnt lgkmcnt(0)" ::: "memory");
#pragma unroll
      for (int r = 0; r < 16; ++r) {
        float sc = sws[w][(r & 3) + 8 * (r >> 2) + 4 * hi];
        o0[r] *= sc; o1[r] *= sc;
      }
    }
    // P = exp2(S - m); per-half row-sum accumulates into lrun partial
    float pA[16], pB[16];
#pragma unroll
    for (int r = 0; r < 16; ++r) {
      pA[r] = __builtin_exp2f(stA[r] - mrun);
      pB[r] = __builtin_exp2f(stB[r] - mrun);
    }
    float sm[8];
#pragma unroll
    for (int i = 0; i < 8; ++i)
      sm[i] = (pA[2 * i] + pA[2 * i + 1]) + (pB[2 * i] + pB[2 * i + 1]);
    lrun += ((sm[0] + sm[1]) + (sm[2] + sm[3])) + ((sm[4] + sm[5]) + (sm[6] + sm[7]));
    // P -> bf16 A-frags; all 8 cross-half exchanges issued in one window
    unsigned dA[8], dB[8];
#pragma unroll
    for (int i = 0; i < 8; ++i) {
      union { bf16 h[2]; unsigned u; } ta, tb;
      ta.h[0] = (bf16)pA[2 * i]; ta.h[1] = (bf16)pA[2 * i + 1];
      tb.h[0] = (bf16)pB[2 * i]; tb.h[1] = (bf16)pB[2 * i + 1];
      dA[i] = ta.u; dB[i] = tb.u;
    }
    unsigned gA02 = (unsigned)__shfl_xor((int)(hi ? dA[0] : dA[2]), 32);
    unsigned gA13 = (unsigned)__shfl_xor((int)(hi ? dA[1] : dA[3]), 32);
    unsigned gA46 = (unsigned)__shfl_xor((int)(hi ? dA[4] : dA[6]), 32);
    unsigned gA57 = (unsigned)__shfl_xor((int)(hi ? dA[5] : dA[7]), 32);
    unsigned gB02 = (unsigned)__shfl_xor((int)(hi ? dB[0] : dB[2]), 32);
    unsigned gB13 = (unsigned)__shfl_xor((int)(hi ? dB[1] : dB[3]), 32);
    unsigned gB46 = (unsigned)__shfl_xor((int)(hi ? dB[4] : dB[6]), 32);
    unsigned gB57 = (unsigned)__shfl_xor((int)(hi ? dB[5] : dB[7]), 32);
    u32x4 wA0 = {hi ? gA02 : dA[0], hi ? gA13 : dA[1], hi ? dA[2] : gA02, hi ? dA[3] : gA13};
    u32x4 wA1 = {hi ? gA46 : dA[4], hi ? gA57 : dA[5], hi ? dA[6] : gA46, hi ? dA[7] : gA57};
    u32x4 wB0 = {hi ? gB02 : dB[0], hi ? gB13 : dB[1], hi ? dB[2] : gB02, hi ? dB[3] : gB13};
    u32x4 wB1 = {hi ? gB46 : dB[4], hi ? gB57 : dB[5], hi ? dB[6] : gB46, hi ? dB[7] : gB57};
    bf16x8 pa0 = __builtin_bit_cast(bf16x8, wA0);
    bf16x8 pa1 = __builtin_bit_cast(bf16x8, wA1);
    bf16x8 pa2 = __builtin_bit_cast(bf16x8, wB0);
    bf16x8 pa3 = __builtin_bit_cast(bf16x8, wB1);
    // O += P @ V (8 MFMAs, two independent accumulators)
    __builtin_amdgcn_s_setprio(1);
    o0 = MFMA32(pa0, bv[0], o0);
    o0 = MFMA32(pa1, bv[1], o0);
    o0 = MFMA32(pa2, bv[2], o0);
    o0 = MFMA32(pa3, bv[3], o0);
    o1 = MFMA32(pa0, bv[4], o1);
    o1 = MFMA32(pa1, bv[5], o1);
    o1 = MFMA32(pa2, bv[6], o1);
    o1 = MFMA32(pa3, bv[7], o1);
    __builtin_amdgcn_s_setprio(0);
  };

  bf16x8 akA[8], akB[8];
  {
    const bf16* Kp = Kbh + (long)col * 64 + hi * 8;
#pragma unroll
    for (int dc = 0; dc < 4; ++dc) {
      akA[dc] = *(const bf16x8*)(Kp + dc * 16);
      akA[4 + dc] = *(const bf16x8*)(Kp + 32 * 64 + dc * 16);
    }
  }
  for (int it = 0; it < 32; it += 2) {
    body(akA, akB, it);
    body(akB, akA, it + 1);
  }

  // finalize: combine per-half lrun, broadcast 1/l q-layout -> d-layout, store
  lrun += __shfl_xor(lrun, 32);
  if (hi == 0) sws[w][col] = 1.0f / lrun;
  asm volatile("s_waitcnt lgkmcnt(0)" ::: "memory");
#pragma unroll
  for (int r = 0; r < 16; ++r) {
    const int qr = (r & 3) + 8 * (r >> 2) + 4 * hi;
    float inv = sws[w][qr];
    long base = ((long)b * 2048 + q0 + qr) * 1024 + h * 64 + col;
    Aout[base] = (bf16)(o0[r] * inv);
    Aout[base + 32] = (bf16)(o1[r] * inv);
  }
}

// ---------------- launcher ----------------
extern "C" void kernel_launch(void* const* d_in, const int* in_sizes, int n_in,
                              void* d_out, int out_size, void* d_ws,
                              size_t ws_size, hipStream_t stream) {
  const float* x    = (const float*)d_in[0];
  const int*   mask = (const int*)d_in[1];
  const float* Wqkv = (const float*)d_in[2];
  const float* bqkv = (const float*)d_in[3];
  const float* Wout = (const float*)d_in[4];
  const float* bout = (const float*)d_in[5];
  float* out = (float*)d_out;

  char* ws = (char*)d_ws;
  bf16* xb    = (bf16*)(ws);                      // 8 MB
  bf16* wqkvT = (bf16*)(ws + (8u << 20));         // 6 MB
  bf16* woutT = (bf16*)(ws + (14u << 20));        // 2 MB
  bf16* Qb    = (bf16*)(ws + (16u << 20));        // 8 MB (b,h,t,d)
  bf16* Kb    = (bf16*)(ws + (24u << 20));        // 8 MB (b,h,t,d)
  bf16* VTb   = (bf16*)(ws + (32u << 20));        // 8 MB (b,h,d,t)
  bf16* Aatt  = xb;

  cast_bf16_kernel<<<4096, 256, 0, stream>>>(x, xb, (4096 * 1024) / 4);
  transpose_cast_kernel<<<dim3(48, 16), 256, 0, stream>>>(Wqkv, wqkvT, 1024, 3072);
  transpose_cast_kernel<<<dim3(16, 16), 256, 0, stream>>>(Wout, woutT, 1024, 1024);
  gemm_bt<0><<<dim3(32, 24), 256, 0, stream>>>(xb, wqkvT, bqkv, Qb, Kb, VTb,
                                               nullptr, 1024);
  attn_kernel<<<512, 256, 0, stream>>>(Qb, Kb, VTb, mask, Aatt);
  gemm_bt<1><<<dim3(32, 8), 256, 0, stream>>>(Aatt, woutT, bout, nullptr,
                                              nullptr, nullptr, out, 1024);
}